// Round 2
// baseline (136.162 us; speedup 1.0000x reference)
//
#include <hip/hip_runtime.h>
#include <math.h>

#define NGRID 4096
#define NQUAD 128
#define NCOMP 16
#define NTERM (NQUAD * NCOMP)

constexpr float SOFTV = 0.01f;
constexpr float GRAV  = 0.004301f;

// workspace layout (float offsets)
constexpr int W_MAX   = 0;   // uint bits of Rmax
constexpr int P_LG0   = 8;
constexpr int P_STEP  = 9;
constexpr int P_ISTEP = 10;
constexpr int P_SCALE = 11;
constexpr int P_SOFT2 = 12;
constexpr int P_MGE   = 13;
constexpr int P_BH    = 14;
constexpr int C_OFF   = 64;
constexpr int A_OFF   = C_OFF + NTERM;        // 64+2048
constexpr int RG_OFF  = A_OFF + NTERM;        // +2048
constexpr int VG_OFF  = RG_OFF + NGRID;       // +4096
// total floats = VG_OFF + 4096 = 12352  (~49 KB of ws)

__global__ void mge_init_kernel(unsigned* ws) {
    if (blockIdx.x == 0 && threadIdx.x == 0) ws[W_MAX] = 0u;
}

__global__ void mge_max_kernel(const float4* __restrict__ Rm, unsigned* ws, int n4) {
    float m = 0.0f;
    int stride = gridDim.x * blockDim.x;
    for (int i = blockIdx.x * blockDim.x + threadIdx.x; i < n4; i += stride) {
        float4 v = Rm[i];
        m = fmaxf(m, fmaxf(fmaxf(v.x, v.y), fmaxf(v.z, v.w)));
    }
    for (int off = 32; off > 0; off >>= 1)
        m = fmaxf(m, __shfl_down(m, off));
    __shared__ float sm[4];
    int lane = threadIdx.x & 63, wid = threadIdx.x >> 6;
    if (lane == 0) sm[wid] = m;
    __syncthreads();
    if (threadIdx.x == 0) {
        m = fmaxf(fmaxf(sm[0], sm[1]), fmaxf(sm[2], sm[3]));
        atomicMax(&ws[W_MAX], __float_as_uint(m));
    }
}

// single block, 128 threads: GL nodes (Newton on P_128, fp64), scalar prep, C/A tables
__global__ void mge_prep_kernel(const float* __restrict__ surf,
                                const float* __restrict__ sigma,
                                const float* __restrict__ qintr,
                                const float* __restrict__ MtoL,
                                const float* __restrict__ inc,
                                const float* __restrict__ mbh,
                                float* __restrict__ ws) {
    __shared__ double xs[64], wq[64];
    __shared__ float md[NCOMP], ssc[NCOMP], qi[NCOMP];
    __shared__ float lo_s, hi_s;
    int tid = threadIdx.x;

    if (tid < 64) {
        const int n = NQUAD;
        double x = cos(M_PI * (tid + 0.75) / (n + 0.5));
        for (int it = 0; it < 30; ++it) {
            double p0 = 1.0, p1 = x;
            for (int k = 2; k <= n; ++k) {
                double p2 = ((2.0 * k - 1.0) * x * p1 - (k - 1.0) * p0) / k;
                p0 = p1; p1 = p2;
            }
            double dP = n * (x * p1 - p0) / (x * x - 1.0);
            double dx = -p1 / dP;
            x += dx;
            if (fabs(dx) < 1e-15) break;
        }
        // final derivative at converged root
        double p0 = 1.0, p1 = x;
        for (int k = 2; k <= n; ++k) {
            double p2 = ((2.0 * k - 1.0) * x * p1 - (k - 1.0) * p0) / k;
            p0 = p1; p1 = p2;
        }
        double dP = n * (x * p1 - p0) / (x * x - 1.0);
        xs[tid] = x;
        wq[tid] = 2.0 / ((1.0 - x * x) * dP * dP);
    }

    if (tid == 0) {
        // median(sigma): insertion sort of 16
        float s[NCOMP];
        for (int i = 0; i < NCOMP; ++i) s[i] = sigma[i];
        for (int i = 1; i < NCOMP; ++i) {
            float v = s[i]; int j = i - 1;
            while (j >= 0 && s[j] > v) { s[j + 1] = s[j]; --j; }
            s[j + 1] = v;
        }
        float scale = 0.5f * (s[7] + s[8]);
        float mds = 0.5f * (s[7] / scale + s[8] / scale);
        float mxs = s[NCOMP - 1] / scale;

        float si = sinf(inc[0]), co = cosf(inc[0]);
        const float inv_sqrt2pi = 0.3989422804014327f;
        for (int k = 0; k < NCOMP; ++k) {
            float q = qintr[k];
            float qobs = sqrtf(q * q * si * si + co * co);
            md[k]  = surf[k] * MtoL[0] * qobs * inv_sqrt2pi / (q * sigma[k]);
            ssc[k] = sigma[k] / scale;
            qi[k]  = q;
        }
        lo_s = asinhf(logf(1e-7f * mds) * (float)(2.0 / M_PI));
        hi_s = asinhf(logf(1000.0f * mxs) * (float)(2.0 / M_PI));

        float Rmax = ws[W_MAX];  // bits written by atomicMax(uint) are float bits
        float lg0 = log10f(SOFTV);
        float lg1 = log10f(Rmax);
        float step = (lg1 - lg0) / (float)(NGRID - 1);
        ws[P_LG0]   = lg0;
        ws[P_STEP]  = step;
        ws[P_ISTEP] = 1.0f / step;
        ws[P_SCALE] = scale;
        float soft_sc = SOFTV / scale;
        ws[P_SOFT2] = soft_sc * soft_sc;
        ws[P_MGE]   = (float)(2.0 * M_PI) * GRAV * scale * scale;
        ws[P_BH]    = GRAV * powf(10.0f, mbh[0]) / scale;
    }
    __syncthreads();

    // per-quadrature-node tables: j = tid (0..127); node = +x for tid<64, -x for tid>=64
    {
        int i = tid & 63;
        float x = (float)xs[i];
        if (tid >= 64) x = -x;
        float w0 = (float)wq[i];
        float half = 0.5f * (hi_s - lo_s);
        float mid  = 0.5f * (hi_s + lo_s);
        float t  = half * x + mid;
        float u  = expf((float)(M_PI / 2.0) * sinhf(t));
        float du = (float)(M_PI / 2.0) * coshf(t) * u;
        float duw = du * (half * w0);
        float op  = 1.0f + u;
        float base = duw / (op * op);
        for (int k = 0; k < NCOMP; ++k) {
            float C = qi[k] * md[k] * base / sqrtf(qi[k] * qi[k] + u);
            float A = -0.5f / (ssc[k] * ssc[k] * op);
            ws[C_OFF + tid * NCOMP + k] = C;
            ws[A_OFF + tid * NCOMP + k] = A;
        }
    }
}

// one wave per grid radius: 4096 waves
__global__ void mge_vgrid_kernel(float* __restrict__ ws) {
    int wid  = (blockIdx.x * blockDim.x + threadIdx.x) >> 6;
    int lane = threadIdx.x & 63;
    float lg0 = ws[P_LG0], step = ws[P_STEP], scale = ws[P_SCALE];
    float R   = exp10f(lg0 + (float)wid * step);
    float Rsc = R / scale;
    float R2  = Rsc * Rsc;
    const float* __restrict__ C = ws + C_OFF;
    const float* __restrict__ A = ws + A_OFF;
    float s = 0.0f;
    for (int t = lane; t < NTERM; t += 64)
        s += C[t] * expf(A[t] * R2);
    for (int off = 32; off > 0; off >>= 1)
        s += __shfl_down(s, off);
    if (lane == 0) {
        float vc2 = ws[P_MGE] * s;
        float x = R2 + ws[P_SOFT2];
        vc2 += ws[P_BH] / (x * sqrtf(x));
        ws[RG_OFF + wid] = R;
        ws[VG_OFF + wid] = Rsc * sqrtf(vc2);
    }
}

__global__ void __launch_bounds__(256) mge_interp_kernel(
        const float4* __restrict__ Rm, float4* __restrict__ out,
        const float* __restrict__ ws, int n4) {
    __shared__ float sg[NGRID];
    __shared__ float sv[NGRID];
    for (int i = threadIdx.x; i < NGRID; i += blockDim.x) {
        sg[i] = ws[RG_OFF + i];
        sv[i] = ws[VG_OFF + i];
    }
    __syncthreads();
    float lg0 = ws[P_LG0], istep = ws[P_ISTEP];
    float g0 = sg[0], gN = sg[NGRID - 1];
    int stride = gridDim.x * blockDim.x;
    for (int idx = blockIdx.x * blockDim.x + threadIdx.x; idx < n4; idx += stride) {
        float4 r4 = Rm[idx];
        float4 o4;
        float* rp = (float*)&r4;
        float* op = (float*)&o4;
        #pragma unroll
        for (int e = 0; e < 4; ++e) {
            float Rc = fminf(fmaxf(rp[e], g0), gN);
            float tpos = (__log10f(Rc) - lg0) * istep;
            int i = (int)ceilf(tpos);
            i = min(max(i, 0), NGRID - 1);
            // exact searchsorted(side='left') fix-up (guess is within +-1)
            while (i < NGRID - 1 && sg[i] < Rc) ++i;
            while (i > 0 && sg[i - 1] >= Rc) --i;
            int lo = max(i - 1, 0);
            float Rlo = sg[lo], Rhi = sg[i];
            float w = (Rhi == Rlo) ? 0.0f : (Rc - Rlo) / (Rhi - Rlo);
            op[e] = sv[lo] + w * (sv[i] - sv[lo]);
        }
        out[idx] = o4;
    }
}

extern "C" void kernel_launch(void* const* d_in, const int* in_sizes, int n_in,
                              void* d_out, int out_size, void* d_ws, size_t ws_size,
                              hipStream_t stream) {
    const float* R_map = (const float*)d_in[0];
    const float* surf  = (const float*)d_in[1];
    const float* sigma = (const float*)d_in[2];
    const float* qintr = (const float*)d_in[3];
    const float* MtoL  = (const float*)d_in[4];
    const float* inc   = (const float*)d_in[5];
    const float* mbh   = (const float*)d_in[6];
    float* out = (float*)d_out;
    float* ws  = (float*)d_ws;

    int n4 = out_size / 4;  // 4096*4096/4

    mge_init_kernel<<<1, 64, 0, stream>>>((unsigned*)d_ws);
    mge_max_kernel<<<2048, 256, 0, stream>>>((const float4*)R_map, (unsigned*)d_ws, n4);
    mge_prep_kernel<<<1, 128, 0, stream>>>(surf, sigma, qintr, MtoL, inc, mbh, ws);
    mge_vgrid_kernel<<<NGRID / 4, 256, 0, stream>>>(ws);
    mge_interp_kernel<<<2048, 256, 0, stream>>>((const float4*)R_map, (float4*)out, ws, n4);
}

// Round 4
// 89.804 us; speedup vs baseline: 1.5162x; 1.5162x over previous
//
#include <hip/hip_runtime.h>
#include <math.h>

#define NGRID 4096
#define NQUAD 128
#define NCOMP 16
#define NTERM (NQUAD * NCOMP)
#define MAXBLOCKS 2048

typedef float f32x4 __attribute__((ext_vector_type(4)));

constexpr float SOFTV = 0.01f;
constexpr float GRAV  = 0.004301f;

// ws float offsets
constexpr int P_FA = 0, P_FB = 1, P_STEP2 = 2, P_LG02 = 3, P_G0 = 4, P_GN = 5,
              P_INVC1 = 6, P_SCALE = 7, P_SOFT2 = 8, P_MGE = 9, P_BH = 10,
              P_LG0 = 11, P_STEP = 12;
constexpr int BM_OFF = 64;                 // 2048 per-block maxima
constexpr int C_OFF  = BM_OFF + MAXBLOCKS; // 2112
constexpr int A_OFF  = C_OFF + NTERM;      // 4160
constexpr int VG_OFF = A_OFF + NTERM;      // 6208 .. 10304 floats (~41 KB)

__global__ void mge_max_kernel(const f32x4* __restrict__ Rm, float* __restrict__ ws, int n4) {
    float m = 0.0f;
    int stride = gridDim.x * blockDim.x;
    for (int i = blockIdx.x * blockDim.x + threadIdx.x; i < n4; i += stride) {
        f32x4 v = Rm[i];
        m = fmaxf(fmaxf(v.x, v.y), fmaxf(fmaxf(v.z, v.w), m));
    }
    for (int off = 32; off > 0; off >>= 1)
        m = fmaxf(m, __shfl_down(m, off));
    __shared__ float sm[4];
    int lane = threadIdx.x & 63, wid = threadIdx.x >> 6;
    if (lane == 0) sm[wid] = m;
    __syncthreads();
    if (threadIdx.x == 0)
        ws[BM_OFF + blockIdx.x] = fmaxf(fmaxf(sm[0], sm[1]), fmaxf(sm[2], sm[3]));
}

// single block, 128 threads
__global__ void mge_prep_kernel(const float* __restrict__ surf,
                                const float* __restrict__ sigma,
                                const float* __restrict__ qintr,
                                const float* __restrict__ MtoL,
                                const float* __restrict__ inc,
                                const float* __restrict__ mbh,
                                float* __restrict__ ws) {
    __shared__ double ak[NQUAD + 1], bk[NQUAD + 1];
    __shared__ double xs[64], wq[64];
    __shared__ float md[NCOMP], ssc[NCOMP], qi[NCOMP];
    __shared__ float lohi[2];
    __shared__ float red[128];
    int tid = threadIdx.x;

    // reduce 2048 per-block maxima
    float m = 0.0f;
    for (int i = tid; i < MAXBLOCKS; i += 128) m = fmaxf(m, ws[BM_OFF + i]);
    red[tid] = m;

    // recurrence coefficients (kills the in-loop fp64 divides)
    if (tid <= NQUAD - 2) {
        int k = tid + 2;
        ak[k] = (2.0 * k - 1.0) / k;
        bk[k] = (k - 1.0) / k;
    }
    __syncthreads();

    // Gauss-Legendre roots: 4 Newton updates + 1 final eval, FMA-only recurrence
    if (tid < 64) {
        double x = cos(M_PI * (tid + 0.75) / (NQUAD + 0.5));
        double p = 0.0, pm = 0.0, dP = 1.0;
        for (int it = 0; it < 5; ++it) {
            pm = 1.0; p = x;
            for (int k = 2; k <= NQUAD; ++k) {
                double p2 = ak[k] * (x * p) - bk[k] * pm;
                pm = p; p = p2;
            }
            dP = NQUAD * (x * p - pm) / (x * x - 1.0);
            if (it < 4) x -= p / dP;
        }
        xs[tid] = x;
        wq[tid] = 2.0 / ((1.0 - x * x) * dP * dP);
    }

    if (tid == 0) {
        float Rmax = red[0];
        for (int i = 1; i < 128; ++i) Rmax = fmaxf(Rmax, red[i]);

        // median(sigma): insertion sort of 16
        float s[NCOMP];
        for (int i = 0; i < NCOMP; ++i) s[i] = sigma[i];
        for (int i = 1; i < NCOMP; ++i) {
            float v = s[i]; int j = i - 1;
            while (j >= 0 && s[j] > v) { s[j + 1] = s[j]; --j; }
            s[j + 1] = v;
        }
        float scale = 0.5f * (s[7] + s[8]);
        float mds = 0.5f * (s[7] / scale + s[8] / scale);
        float mxs = s[NCOMP - 1] / scale;

        float si = sinf(inc[0]), co = cosf(inc[0]);
        const float inv_sqrt2pi = 0.3989422804014327f;
        for (int k = 0; k < NCOMP; ++k) {
            float q = qintr[k];
            float qobs = sqrtf(q * q * si * si + co * co);
            md[k]  = surf[k] * MtoL[0] * qobs * inv_sqrt2pi / (q * sigma[k]);
            ssc[k] = sigma[k] / scale;
            qi[k]  = q;
        }
        lohi[0] = asinhf(logf(1e-7f * mds) * (float)(2.0 / M_PI));
        lohi[1] = asinhf(logf(1000.0f * mxs) * (float)(2.0 / M_PI));

        const float L2T = 3.321928094887362f;   // log2(10)
        const float LT2 = 0.3010299956639812f;  // log10(2)
        float lg0 = log10f(SOFTV);
        float lg1 = log10f(Rmax);
        float step = (lg1 - lg0) / (float)(NGRID - 1);
        float istep = 1.0f / step;
        ws[P_FA]    = LT2 * istep;
        ws[P_FB]    = -lg0 * istep;
        ws[P_STEP2] = step * L2T;
        ws[P_LG02]  = lg0 * L2T;
        ws[P_G0]    = exp2f(lg0 * L2T);
        ws[P_GN]    = exp2f((lg0 + step * (float)(NGRID - 1)) * L2T);
        double c1 = exp((double)step * 2.302585092994045684) - 1.0;
        ws[P_INVC1] = (float)(1.0 / c1);
        ws[P_SCALE] = scale;
        float soft_sc = SOFTV / scale;
        ws[P_SOFT2] = soft_sc * soft_sc;
        ws[P_MGE]   = (float)(2.0 * M_PI) * GRAV * scale * scale;
        ws[P_BH]    = GRAV * exp2f(mbh[0] * L2T) / scale;
        ws[P_LG0]   = lg0;
        ws[P_STEP]  = step;
    }
    __syncthreads();

    // per-quadrature-node C/A tables (tid 0..127 = node j; +x for tid<64, -x for tid>=64)
    {
        int i = tid & 63;
        float x = (float)xs[i];
        if (tid >= 64) x = -x;
        float w0 = (float)wq[i];
        float half = 0.5f * (lohi[1] - lohi[0]);
        float mid  = 0.5f * (lohi[1] + lohi[0]);
        float t  = half * x + mid;
        float u  = expf((float)(M_PI / 2.0) * sinhf(t));
        float du = (float)(M_PI / 2.0) * coshf(t) * u;
        float duw = du * (half * w0);
        float op  = 1.0f + u;
        float base = duw / (op * op);
        for (int k = 0; k < NCOMP; ++k) {
            ws[C_OFF + tid * NCOMP + k] = qi[k] * md[k] * base / sqrtf(qi[k] * qi[k] + u);
            ws[A_OFF + tid * NCOMP + k] = -0.5f / (ssc[k] * ssc[k] * op);
        }
    }
}

// one wave per grid radius: 4096 waves
__global__ void mge_vgrid_kernel(float* __restrict__ ws) {
    int wid  = (blockIdx.x * blockDim.x + threadIdx.x) >> 6;
    int lane = threadIdx.x & 63;
    const float L2T = 3.321928094887362f;
    float lg0 = ws[P_LG0], step = ws[P_STEP], scale = ws[P_SCALE];
    float R   = exp2f((lg0 + (float)wid * step) * L2T);
    float Rsc = R / scale;
    float R2  = Rsc * Rsc;
    const float* __restrict__ C = ws + C_OFF;
    const float* __restrict__ A = ws + A_OFF;
    float s = 0.0f;
    for (int t = lane; t < NTERM; t += 64)
        s += C[t] * __expf(A[t] * R2);
    for (int off = 32; off > 0; off >>= 1)
        s += __shfl_down(s, off);
    if (lane == 0) {
        float vc2 = ws[P_MGE] * s;
        float xq = R2 + ws[P_SOFT2];
        vc2 += ws[P_BH] / (xq * sqrtf(xq));
        ws[VG_OFF + wid] = Rsc * sqrtf(vc2);
    }
}

__global__ void __launch_bounds__(256) mge_interp_kernel(
        const f32x4* __restrict__ Rm, f32x4* __restrict__ out,
        const float* __restrict__ ws, int n4) {
    __shared__ float2 tbl[NGRID];   // (v[i], v[i+1]-v[i]) -> single ds_read_b64
    const float* __restrict__ vg = ws + VG_OFF;
    for (int i = threadIdx.x; i < NGRID; i += 256) {
        float v0 = vg[i];
        float v1 = (i < NGRID - 1) ? vg[i + 1] : v0;
        tbl[i] = make_float2(v0, v1 - v0);
    }
    __syncthreads();
    float fa = ws[P_FA], fb = ws[P_FB];
    float step2 = ws[P_STEP2], lg02 = ws[P_LG02];
    float g0 = ws[P_G0], gN = ws[P_GN], invc1 = ws[P_INVC1];
    int stride = gridDim.x * blockDim.x;
    for (int idx = blockIdx.x * blockDim.x + threadIdx.x; idx < n4; idx += stride) {
        f32x4 r4 = Rm[idx];
        f32x4 o4;
        #pragma unroll
        for (int e = 0; e < 4; ++e) {
            float Rc = fminf(fmaxf(r4[e], g0), gN);
            // analytic searchsorted on the exact-exponential grid
            float f = fmaf(__log2f(Rc), fa, fb);
            int lo = (int)ceilf(f) - 1;
            lo = min(max(lo, 0), NGRID - 2);
            float Rlo = exp2f(fmaf((float)lo, step2, lg02));
            float w = fmaf(Rc, __builtin_amdgcn_rcpf(Rlo), -1.0f) * invc1;
            float2 tv = tbl[lo];
            o4[e] = fmaf(w, tv.y, tv.x);
        }
        __builtin_nontemporal_store(o4, &out[idx]);
    }
}

extern "C" void kernel_launch(void* const* d_in, const int* in_sizes, int n_in,
                              void* d_out, int out_size, void* d_ws, size_t ws_size,
                              hipStream_t stream) {
    const float* R_map = (const float*)d_in[0];
    const float* surf  = (const float*)d_in[1];
    const float* sigma = (const float*)d_in[2];
    const float* qintr = (const float*)d_in[3];
    const float* MtoL  = (const float*)d_in[4];
    const float* inc   = (const float*)d_in[5];
    const float* mbh   = (const float*)d_in[6];
    float* out = (float*)d_out;
    float* ws  = (float*)d_ws;

    int n4 = out_size / 4;

    mge_max_kernel<<<MAXBLOCKS, 256, 0, stream>>>((const f32x4*)R_map, ws, n4);
    mge_prep_kernel<<<1, 128, 0, stream>>>(surf, sigma, qintr, MtoL, inc, mbh, ws);
    mge_vgrid_kernel<<<NGRID / 4, 256, 0, stream>>>(ws);
    mge_interp_kernel<<<2048, 256, 0, stream>>>((const f32x4*)R_map, (f32x4*)out, ws, n4);
}

// Round 5
// 77.300 us; speedup vs baseline: 1.7615x; 1.1617x over previous
//
#include <hip/hip_runtime.h>
#include <math.h>

#define NGRID 4096
#define NQUAD 128
#define NCOMP 16
#define NTERM (NQUAD * NCOMP)
#define MAXBLOCKS 2048

typedef float f32x4 __attribute__((ext_vector_type(4)));

constexpr float SOFTV = 0.01f;
constexpr float GRAV  = 0.004301f;

// compile-time Legendre recurrence coefficients: a[k]=(2k-1)/k, b[k]=(k-1)/k
struct GLC_t { double a[NQUAD + 1]; double b[NQUAD + 1]; };
constexpr GLC_t glc_init() {
    GLC_t c{};
    for (int k = 2; k <= NQUAD; ++k) {
        c.a[k] = (2.0 * k - 1.0) / (double)k;
        c.b[k] = (k - 1.0) / (double)k;
    }
    return c;
}
constexpr GLC_t GLC = glc_init();

// ws float offsets
constexpr int P_FA = 0, P_FB = 1, P_STEP2 = 2, P_LG02 = 3, P_G0 = 4, P_GN = 5,
              P_INVC1 = 6, P_SCALE = 7, P_SOFT2 = 8, P_MGE = 9, P_BH = 10,
              P_LG0 = 11, P_STEP = 12;
constexpr int BM_OFF = 64;                 // 2048 per-block maxima
constexpr int C_OFF  = BM_OFF + MAXBLOCKS; // 2112
constexpr int A_OFF  = C_OFF + NTERM;      // 4160
constexpr int VG_OFF = A_OFF + NTERM;      // 6208 .. 10304 floats (~41 KB)

__global__ void mge_max_kernel(const f32x4* __restrict__ Rm, float* __restrict__ ws, int n4) {
    float m = 0.0f;
    int stride = gridDim.x * blockDim.x;
    for (int i = blockIdx.x * blockDim.x + threadIdx.x; i < n4; i += stride) {
        f32x4 v = Rm[i];
        m = fmaxf(fmaxf(v.x, v.y), fmaxf(fmaxf(v.z, v.w), m));
    }
    for (int off = 32; off > 0; off >>= 1)
        m = fmaxf(m, __shfl_down(m, off));
    __shared__ float sm[4];
    int lane = threadIdx.x & 63, wid = threadIdx.x >> 6;
    if (lane == 0) sm[wid] = m;
    __syncthreads();
    if (threadIdx.x == 0)
        ws[BM_OFF + blockIdx.x] = fmaxf(fmaxf(sm[0], sm[1]), fmaxf(sm[2], sm[3]));
}

// single block, 128 threads
__global__ void mge_prep_kernel(const float* __restrict__ surf,
                                const float* __restrict__ sigma,
                                const float* __restrict__ qintr,
                                const float* __restrict__ MtoL,
                                const float* __restrict__ inc,
                                const float* __restrict__ mbh,
                                float* __restrict__ ws) {
    __shared__ double xs[64], wq[64];
    __shared__ float md[NCOMP], ssc[NCOMP], qi[NCOMP];
    __shared__ float lohi[2];
    __shared__ float red[128];
    int tid = threadIdx.x;

    // reduce 2048 per-block maxima
    float m = 0.0f;
    for (int i = tid; i < MAXBLOCKS; i += 128) m = fmaxf(m, ws[BM_OFF + i]);
    red[tid] = m;

    // Gauss-Legendre roots: 3 Newton updates + 1 final eval.
    // Coefficients are constexpr + full unroll -> immediates, no LDS, no divides.
    if (tid < 64) {
        double x = cos(M_PI * (tid + 0.75) / (NQUAD + 0.5));
        double p = 0.0, pm = 0.0, dP = 1.0;
        for (int it = 0; it < 4; ++it) {
            pm = 1.0; p = x;
            #pragma unroll
            for (int k = 2; k <= NQUAD; ++k) {
                double p2 = GLC.a[k] * (x * p) - GLC.b[k] * pm;
                pm = p; p = p2;
            }
            dP = NQUAD * (x * p - pm) / (x * x - 1.0);
            if (it < 3) x -= p / dP;
        }
        xs[tid] = x;
        wq[tid] = 2.0 / ((1.0 - x * x) * dP * dP);
    }

    if (tid == 64) {
        // median(sigma): insertion sort of 16 (runs concurrently with Newton wave)
        float s[NCOMP];
        for (int i = 0; i < NCOMP; ++i) s[i] = sigma[i];
        for (int i = 1; i < NCOMP; ++i) {
            float v = s[i]; int j = i - 1;
            while (j >= 0 && s[j] > v) { s[j + 1] = s[j]; --j; }
            s[j + 1] = v;
        }
        float scale = 0.5f * (s[7] + s[8]);
        float mds = 0.5f * (s[7] / scale + s[8] / scale);
        float mxs = s[NCOMP - 1] / scale;

        float si = sinf(inc[0]), co = cosf(inc[0]);
        const float inv_sqrt2pi = 0.3989422804014327f;
        for (int k = 0; k < NCOMP; ++k) {
            float q = qintr[k];
            float qobs = sqrtf(q * q * si * si + co * co);
            md[k]  = surf[k] * MtoL[0] * qobs * inv_sqrt2pi / (q * sigma[k]);
            ssc[k] = sigma[k] / scale;
            qi[k]  = q;
        }
        lohi[0] = asinhf(logf(1e-7f * mds) * (float)(2.0 / M_PI));
        lohi[1] = asinhf(logf(1000.0f * mxs) * (float)(2.0 / M_PI));

        ws[P_SCALE] = scale;
        float soft_sc = SOFTV / scale;
        ws[P_SOFT2] = soft_sc * soft_sc;
        ws[P_MGE]   = (float)(2.0 * M_PI) * GRAV * scale * scale;
        const float L2T = 3.321928094887362f;   // log2(10)
        ws[P_BH]    = GRAV * exp2f(mbh[0] * L2T) / scale;
    }
    __syncthreads();

    if (tid == 0) {
        float Rmax = red[0];
        for (int i = 1; i < 128; ++i) Rmax = fmaxf(Rmax, red[i]);
        const float L2T = 3.321928094887362f;   // log2(10)
        const float LT2 = 0.3010299956639812f;  // log10(2)
        float lg0 = log10f(SOFTV);
        float lg1 = log10f(Rmax);
        float step = (lg1 - lg0) / (float)(NGRID - 1);
        float istep = 1.0f / step;
        ws[P_FA]    = LT2 * istep;
        ws[P_FB]    = -lg0 * istep;
        ws[P_STEP2] = step * L2T;
        ws[P_LG02]  = lg0 * L2T;
        ws[P_G0]    = exp2f(lg0 * L2T);
        ws[P_GN]    = exp2f((lg0 + step * (float)(NGRID - 1)) * L2T);
        double c1 = exp((double)step * 2.302585092994045684) - 1.0;
        ws[P_INVC1] = (float)(1.0 / c1);
        ws[P_LG0]   = lg0;
        ws[P_STEP]  = step;
    }

    // per-quadrature-node C/A tables (tid 0..127 = node j; +x for tid<64, -x for tid>=64)
    {
        int i = tid & 63;
        float x = (float)xs[i];
        if (tid >= 64) x = -x;
        float w0 = (float)wq[i];
        float half = 0.5f * (lohi[1] - lohi[0]);
        float mid  = 0.5f * (lohi[1] + lohi[0]);
        float t  = half * x + mid;
        float u  = expf((float)(M_PI / 2.0) * sinhf(t));
        float du = (float)(M_PI / 2.0) * coshf(t) * u;
        float duw = du * (half * w0);
        float op  = 1.0f + u;
        float base = duw / (op * op);
        for (int k = 0; k < NCOMP; ++k) {
            ws[C_OFF + tid * NCOMP + k] = qi[k] * md[k] * base / sqrtf(qi[k] * qi[k] + u);
            ws[A_OFF + tid * NCOMP + k] = -0.5f / (ssc[k] * ssc[k] * op);
        }
    }
}

// one wave per grid radius: 4096 waves
__global__ void mge_vgrid_kernel(float* __restrict__ ws) {
    int wid  = (blockIdx.x * blockDim.x + threadIdx.x) >> 6;
    int lane = threadIdx.x & 63;
    const float L2T = 3.321928094887362f;
    float lg0 = ws[P_LG0], step = ws[P_STEP], scale = ws[P_SCALE];
    float R   = exp2f((lg0 + (float)wid * step) * L2T);
    float Rsc = R / scale;
    float R2  = Rsc * Rsc;
    const float* __restrict__ C = ws + C_OFF;
    const float* __restrict__ A = ws + A_OFF;
    float s = 0.0f;
    for (int t = lane; t < NTERM; t += 64)
        s += C[t] * __expf(A[t] * R2);
    for (int off = 32; off > 0; off >>= 1)
        s += __shfl_down(s, off);
    if (lane == 0) {
        float vc2 = ws[P_MGE] * s;
        float xq = R2 + ws[P_SOFT2];
        vc2 += ws[P_BH] / (xq * sqrtf(xq));
        ws[VG_OFF + wid] = Rsc * sqrtf(vc2);
    }
}

__global__ void __launch_bounds__(256) mge_interp_kernel(
        const f32x4* __restrict__ Rm, f32x4* __restrict__ out,
        const float* __restrict__ ws, int n4) {
    __shared__ float2 tbl[NGRID];   // (v[i], v[i+1]-v[i]) -> single ds_read_b64
    const float* __restrict__ vg = ws + VG_OFF;
    for (int i = threadIdx.x; i < NGRID; i += 256) {
        float v0 = vg[i];
        float v1 = (i < NGRID - 1) ? vg[i + 1] : v0;
        tbl[i] = make_float2(v0, v1 - v0);
    }
    __syncthreads();
    float fa = ws[P_FA], fb = ws[P_FB];
    float step2 = ws[P_STEP2], lg02 = ws[P_LG02];
    float g0 = ws[P_G0], gN = ws[P_GN], invc1 = ws[P_INVC1];
    int stride = gridDim.x * blockDim.x;
    for (int idx = blockIdx.x * blockDim.x + threadIdx.x; idx < n4; idx += stride) {
        f32x4 r4 = Rm[idx];
        f32x4 o4;
        #pragma unroll
        for (int e = 0; e < 4; ++e) {
            float Rc = fminf(fmaxf(r4[e], g0), gN);
            // analytic searchsorted on the exact-exponential grid
            float f = fmaf(__log2f(Rc), fa, fb);
            int lo = (int)ceilf(f) - 1;
            lo = min(max(lo, 0), NGRID - 2);
            float Rlo = exp2f(fmaf((float)lo, step2, lg02));
            float w = fmaf(Rc, __builtin_amdgcn_rcpf(Rlo), -1.0f) * invc1;
            float2 tv = tbl[lo];
            o4[e] = fmaf(w, tv.y, tv.x);
        }
        __builtin_nontemporal_store(o4, &out[idx]);
    }
}

extern "C" void kernel_launch(void* const* d_in, const int* in_sizes, int n_in,
                              void* d_out, int out_size, void* d_ws, size_t ws_size,
                              hipStream_t stream) {
    const float* R_map = (const float*)d_in[0];
    const float* surf  = (const float*)d_in[1];
    const float* sigma = (const float*)d_in[2];
    const float* qintr = (const float*)d_in[3];
    const float* MtoL  = (const float*)d_in[4];
    const float* inc   = (const float*)d_in[5];
    const float* mbh   = (const float*)d_in[6];
    float* out = (float*)d_out;
    float* ws  = (float*)d_ws;

    int n4 = out_size / 4;

    mge_max_kernel<<<MAXBLOCKS, 256, 0, stream>>>((const f32x4*)R_map, ws, n4);
    mge_prep_kernel<<<1, 128, 0, stream>>>(surf, sigma, qintr, MtoL, inc, mbh, ws);
    mge_vgrid_kernel<<<NGRID / 4, 256, 0, stream>>>(ws);
    mge_interp_kernel<<<2048, 256, 0, stream>>>((const f32x4*)R_map, (f32x4*)out, ws, n4);
}

// Round 6
// 75.119 us; speedup vs baseline: 1.8126x; 1.0290x over previous
//
#include <hip/hip_runtime.h>
#include <math.h>

#define NGRID 4096
#define NQUAD 128
#define NCOMP 16
#define NTERM (NQUAD * NCOMP)
#define MAXBLOCKS 2048

typedef float f32x4 __attribute__((ext_vector_type(4)));

constexpr float SOFTV = 0.01f;
constexpr float GRAV  = 0.004301f;

// ---- compile-time Gauss-Legendre nodes (no runtime dependence at all) ----
constexpr double ccos(double x) {
    // Taylor series; |x| < 1.6 rad -> term 20 ~ 5e-27, fp64-exact
    double t = 1.0, s = 1.0, x2 = x * x;
    for (int k = 1; k <= 20; ++k) {
        t *= -x2 / ((2.0 * k - 1.0) * (2.0 * k));
        s += t;
    }
    return s;
}
struct GLNodes { float x[64]; float w[64]; };
constexpr GLNodes gl_init() {
    GLNodes g{};
    for (int i = 0; i < 64; ++i) {
        double x = ccos(3.14159265358979323846 * (i + 0.75) / (NQUAD + 0.5));
        double p = 0.0, pm = 0.0, dP = 1.0;
        for (int it = 0; it < 4; ++it) {
            pm = 1.0; p = x;
            for (int k = 2; k <= NQUAD; ++k) {
                double p2 = ((2.0 * k - 1.0) * x * p - (k - 1.0) * pm) / (double)k;
                pm = p; p = p2;
            }
            dP = (double)NQUAD * (x * p - pm) / (x * x - 1.0);
            if (it < 3) x -= p / dP;
        }
        g.x[i] = (float)x;
        g.w[i] = (float)(2.0 / ((1.0 - x * x) * dP * dP));
    }
    return g;
}
constexpr GLNodes GL = gl_init();

// ws float offsets
constexpr int P_FA = 0, P_FB = 1, P_STEP2 = 2, P_LG02 = 3, P_G0 = 4, P_GN = 5,
              P_INVC1 = 6, P_SCALE = 7, P_SOFT2 = 8, P_MGE = 9, P_BH = 10,
              P_LG0 = 11, P_STEP = 12;
constexpr int BM_OFF = 64;                 // 2048 per-block maxima
constexpr int C_OFF  = BM_OFF + MAXBLOCKS; // 2112
constexpr int A_OFF  = C_OFF + NTERM;      // 4160
constexpr int VG_OFF = A_OFF + NTERM;      // 6208 .. 10304 floats (~41 KB)

__global__ void mge_max_kernel(const f32x4* __restrict__ Rm, float* __restrict__ ws, int n4) {
    float m = 0.0f;
    int stride = gridDim.x * blockDim.x;
    for (int i = blockIdx.x * blockDim.x + threadIdx.x; i < n4; i += stride) {
        f32x4 v = Rm[i];
        m = fmaxf(fmaxf(v.x, v.y), fmaxf(fmaxf(v.z, v.w), m));
    }
    for (int off = 32; off > 0; off >>= 1)
        m = fmaxf(m, __shfl_down(m, off));
    __shared__ float sm[4];
    int lane = threadIdx.x & 63, wid = threadIdx.x >> 6;
    if (lane == 0) sm[wid] = m;
    __syncthreads();
    if (threadIdx.x == 0)
        ws[BM_OFF + blockIdx.x] = fmaxf(fmaxf(sm[0], sm[1]), fmaxf(sm[2], sm[3]));
}

// single block, 128 threads — no Newton anymore, nodes are compile-time
__global__ void mge_prep_kernel(const float* __restrict__ surf,
                                const float* __restrict__ sigma,
                                const float* __restrict__ qintr,
                                const float* __restrict__ MtoL,
                                const float* __restrict__ inc,
                                const float* __restrict__ mbh,
                                float* __restrict__ ws) {
    __shared__ float md[NCOMP], ssc[NCOMP], qi[NCOMP];
    __shared__ float lohi[2];
    __shared__ float red[128];
    int tid = threadIdx.x;

    // reduce 2048 per-block maxima
    float m = 0.0f;
    for (int i = tid; i < MAXBLOCKS; i += 128) m = fmaxf(m, ws[BM_OFF + i]);
    red[tid] = m;

    if (tid == 64) {
        // median(sigma): insertion sort of 16
        float s[NCOMP];
        for (int i = 0; i < NCOMP; ++i) s[i] = sigma[i];
        for (int i = 1; i < NCOMP; ++i) {
            float v = s[i]; int j = i - 1;
            while (j >= 0 && s[j] > v) { s[j + 1] = s[j]; --j; }
            s[j + 1] = v;
        }
        float scale = 0.5f * (s[7] + s[8]);
        float mds = 0.5f * (s[7] / scale + s[8] / scale);
        float mxs = s[NCOMP - 1] / scale;

        float si = sinf(inc[0]), co = cosf(inc[0]);
        const float inv_sqrt2pi = 0.3989422804014327f;
        for (int k = 0; k < NCOMP; ++k) {
            float q = qintr[k];
            float qobs = sqrtf(q * q * si * si + co * co);
            md[k]  = surf[k] * MtoL[0] * qobs * inv_sqrt2pi / (q * sigma[k]);
            ssc[k] = sigma[k] / scale;
            qi[k]  = q;
        }
        lohi[0] = asinhf(logf(1e-7f * mds) * (float)(2.0 / M_PI));
        lohi[1] = asinhf(logf(1000.0f * mxs) * (float)(2.0 / M_PI));

        ws[P_SCALE] = scale;
        float soft_sc = SOFTV / scale;
        ws[P_SOFT2] = soft_sc * soft_sc;
        ws[P_MGE]   = (float)(2.0 * M_PI) * GRAV * scale * scale;
        const float L2T = 3.321928094887362f;   // log2(10)
        ws[P_BH]    = GRAV * exp2f(mbh[0] * L2T) / scale;
    }
    __syncthreads();

    if (tid == 0) {
        float Rmax = red[0];
        for (int i = 1; i < 128; ++i) Rmax = fmaxf(Rmax, red[i]);
        const float L2T = 3.321928094887362f;   // log2(10)
        const float LT2 = 0.3010299956639812f;  // log10(2)
        float lg0 = log10f(SOFTV);
        float lg1 = log10f(Rmax);
        float step = (lg1 - lg0) / (float)(NGRID - 1);
        float istep = 1.0f / step;
        ws[P_FA]    = LT2 * istep;
        ws[P_FB]    = -lg0 * istep;
        ws[P_STEP2] = step * L2T;
        ws[P_LG02]  = lg0 * L2T;
        ws[P_G0]    = exp2f(lg0 * L2T);
        ws[P_GN]    = exp2f((lg0 + step * (float)(NGRID - 1)) * L2T);
        double c1 = exp((double)step * 2.302585092994045684) - 1.0;
        ws[P_INVC1] = (float)(1.0 / c1);
        ws[P_LG0]   = lg0;
        ws[P_STEP]  = step;
    }

    // per-quadrature-node C/A tables (tid 0..127 = node j; +x for tid<64, -x for tid>=64)
    {
        int i = tid & 63;
        float x = GL.x[i];
        if (tid >= 64) x = -x;
        float w0 = GL.w[i];
        float half = 0.5f * (lohi[1] - lohi[0]);
        float mid  = 0.5f * (lohi[1] + lohi[0]);
        float t  = half * x + mid;
        float u  = expf((float)(M_PI / 2.0) * sinhf(t));
        float du = (float)(M_PI / 2.0) * coshf(t) * u;
        float duw = du * (half * w0);
        float op  = 1.0f + u;
        float base = duw / (op * op);
        for (int k = 0; k < NCOMP; ++k) {
            ws[C_OFF + tid * NCOMP + k] = qi[k] * md[k] * base / sqrtf(qi[k] * qi[k] + u);
            ws[A_OFF + tid * NCOMP + k] = -0.5f / (ssc[k] * ssc[k] * op);
        }
    }
}

// one wave per grid radius: 4096 waves
__global__ void mge_vgrid_kernel(float* __restrict__ ws) {
    int wid  = (blockIdx.x * blockDim.x + threadIdx.x) >> 6;
    int lane = threadIdx.x & 63;
    const float L2T = 3.321928094887362f;
    float lg0 = ws[P_LG0], step = ws[P_STEP], scale = ws[P_SCALE];
    float R   = exp2f((lg0 + (float)wid * step) * L2T);
    float Rsc = R / scale;
    float R2  = Rsc * Rsc;
    const float* __restrict__ C = ws + C_OFF;
    const float* __restrict__ A = ws + A_OFF;
    float s = 0.0f;
    for (int t = lane; t < NTERM; t += 64)
        s += C[t] * __expf(A[t] * R2);
    for (int off = 32; off > 0; off >>= 1)
        s += __shfl_down(s, off);
    if (lane == 0) {
        float vc2 = ws[P_MGE] * s;
        float xq = R2 + ws[P_SOFT2];
        vc2 += ws[P_BH] / (xq * sqrtf(xq));
        ws[VG_OFF + wid] = Rsc * sqrtf(vc2);
    }
}

__global__ void __launch_bounds__(256) mge_interp_kernel(
        const f32x4* __restrict__ Rm, f32x4* __restrict__ out,
        const float* __restrict__ ws, int n4) {
    __shared__ float tv[NGRID];  // v[i]        (stride-1: all 32 banks)
    __shared__ float td[NGRID];  // v[i+1]-v[i]
    const float* __restrict__ vg = ws + VG_OFF;
    for (int i = threadIdx.x; i < NGRID; i += 256) {
        float v0 = vg[i];
        float v1 = (i < NGRID - 1) ? vg[i + 1] : v0;
        tv[i] = v0;
        td[i] = v1 - v0;
    }
    __syncthreads();
    float fa = ws[P_FA], fb = ws[P_FB];
    float step2 = ws[P_STEP2], lg02 = ws[P_LG02];
    float g0 = ws[P_G0], gN = ws[P_GN], invc1 = ws[P_INVC1];
    int stride = gridDim.x * blockDim.x;
    for (int idx = blockIdx.x * blockDim.x + threadIdx.x; idx < n4; idx += stride) {
        f32x4 r4 = Rm[idx];
        f32x4 o4;
        #pragma unroll
        for (int e = 0; e < 4; ++e) {
            float Rc = fminf(fmaxf(r4[e], g0), gN);
            // analytic searchsorted on the exact-exponential grid
            float f = fmaf(__log2f(Rc), fa, fb);
            int lo = (int)ceilf(f) - 1;
            lo = min(max(lo, 0), NGRID - 2);
            float Rlo = exp2f(fmaf((float)lo, step2, lg02));
            float w = fmaf(Rc, __builtin_amdgcn_rcpf(Rlo), -1.0f) * invc1;
            o4[e] = fmaf(w, td[lo], tv[lo]);
        }
        __builtin_nontemporal_store(o4, &out[idx]);
    }
}

extern "C" void kernel_launch(void* const* d_in, const int* in_sizes, int n_in,
                              void* d_out, int out_size, void* d_ws, size_t ws_size,
                              hipStream_t stream) {
    const float* R_map = (const float*)d_in[0];
    const float* surf  = (const float*)d_in[1];
    const float* sigma = (const float*)d_in[2];
    const float* qintr = (const float*)d_in[3];
    const float* MtoL  = (const float*)d_in[4];
    const float* inc   = (const float*)d_in[5];
    const float* mbh   = (const float*)d_in[6];
    float* out = (float*)d_out;
    float* ws  = (float*)d_ws;

    int n4 = out_size / 4;

    mge_max_kernel<<<MAXBLOCKS, 256, 0, stream>>>((const f32x4*)R_map, ws, n4);
    mge_prep_kernel<<<1, 128, 0, stream>>>(surf, sigma, qintr, MtoL, inc, mbh, ws);
    mge_vgrid_kernel<<<NGRID / 4, 256, 0, stream>>>(ws);
    mge_interp_kernel<<<2048, 256, 0, stream>>>((const f32x4*)R_map, (f32x4*)out, ws, n4);
}

// Round 7
// 63.812 us; speedup vs baseline: 2.1338x; 1.1772x over previous
//
#include <hip/hip_runtime.h>
#include <math.h>

#define NGRID 4096
#define NQUAD 128
#define NCOMP 16
#define NTERM (NQUAD * NCOMP)
#define MAXBLOCKS 2048

typedef float f32x4 __attribute__((ext_vector_type(4)));

constexpr float SOFTV = 0.01f;
constexpr float GRAV  = 0.004301f;

// ---- compile-time Gauss-Legendre nodes (no runtime dependence at all) ----
constexpr double ccos(double x) {
    double t = 1.0, s = 1.0, x2 = x * x;
    for (int k = 1; k <= 20; ++k) {
        t *= -x2 / ((2.0 * k - 1.0) * (2.0 * k));
        s += t;
    }
    return s;
}
struct GLNodes { float x[64]; float w[64]; };
constexpr GLNodes gl_init() {
    GLNodes g{};
    for (int i = 0; i < 64; ++i) {
        double x = ccos(3.14159265358979323846 * (i + 0.75) / (NQUAD + 0.5));
        double p = 0.0, pm = 0.0, dP = 1.0;
        for (int it = 0; it < 4; ++it) {
            pm = 1.0; p = x;
            for (int k = 2; k <= NQUAD; ++k) {
                double p2 = ((2.0 * k - 1.0) * x * p - (k - 1.0) * pm) / (double)k;
                pm = p; p = p2;
            }
            dP = (double)NQUAD * (x * p - pm) / (x * x - 1.0);
            if (it < 3) x -= p / dP;
        }
        g.x[i] = (float)x;
        g.w[i] = (float)(2.0 / ((1.0 - x * x) * dP * dP));
    }
    return g;
}
constexpr GLNodes GL = gl_init();

// ws float offsets
constexpr int P_FA = 0, P_FB = 1, P_SCALE = 2, P_SOFT2 = 3, P_MGE = 4, P_BH = 5,
              P_LG0 = 6, P_STEP = 7;
constexpr int BM_OFF = 64;                 // 2048 per-block maxima
constexpr int C_OFF  = BM_OFF + MAXBLOCKS; // 2112
constexpr int A_OFF  = C_OFF + NTERM;      // 4160
constexpr int VG_OFF = A_OFF + NTERM;      // 6208 .. 10304 floats (~41 KB)

__global__ void mge_max_kernel(const f32x4* __restrict__ Rm, float* __restrict__ ws, int n4) {
    float m = 0.0f;
    int stride = gridDim.x * blockDim.x;
    for (int i = blockIdx.x * blockDim.x + threadIdx.x; i < n4; i += stride) {
        f32x4 v = Rm[i];
        m = fmaxf(fmaxf(v.x, v.y), fmaxf(fmaxf(v.z, v.w), m));
    }
    for (int off = 32; off > 0; off >>= 1)
        m = fmaxf(m, __shfl_down(m, off));
    __shared__ float sm[4];
    int lane = threadIdx.x & 63, wid = threadIdx.x >> 6;
    if (lane == 0) sm[wid] = m;
    __syncthreads();
    if (threadIdx.x == 0)
        ws[BM_OFF + blockIdx.x] = fmaxf(fmaxf(sm[0], sm[1]), fmaxf(sm[2], sm[3]));
}

// single block, 128 threads — nodes are compile-time
__global__ void mge_prep_kernel(const float* __restrict__ surf,
                                const float* __restrict__ sigma,
                                const float* __restrict__ qintr,
                                const float* __restrict__ MtoL,
                                const float* __restrict__ inc,
                                const float* __restrict__ mbh,
                                float* __restrict__ ws) {
    __shared__ float md[NCOMP], ssc[NCOMP], qi[NCOMP];
    __shared__ float lohi[2];
    __shared__ float red[128];
    int tid = threadIdx.x;

    // reduce 2048 per-block maxima
    float m = 0.0f;
    for (int i = tid; i < MAXBLOCKS; i += 128) m = fmaxf(m, ws[BM_OFF + i]);
    red[tid] = m;

    if (tid == 64) {
        // median(sigma): insertion sort of 16
        float s[NCOMP];
        for (int i = 0; i < NCOMP; ++i) s[i] = sigma[i];
        for (int i = 1; i < NCOMP; ++i) {
            float v = s[i]; int j = i - 1;
            while (j >= 0 && s[j] > v) { s[j + 1] = s[j]; --j; }
            s[j + 1] = v;
        }
        float scale = 0.5f * (s[7] + s[8]);
        float mds = 0.5f * (s[7] / scale + s[8] / scale);
        float mxs = s[NCOMP - 1] / scale;

        float si = sinf(inc[0]), co = cosf(inc[0]);
        const float inv_sqrt2pi = 0.3989422804014327f;
        for (int k = 0; k < NCOMP; ++k) {
            float q = qintr[k];
            float qobs = sqrtf(q * q * si * si + co * co);
            md[k]  = surf[k] * MtoL[0] * qobs * inv_sqrt2pi / (q * sigma[k]);
            ssc[k] = sigma[k] / scale;
            qi[k]  = q;
        }
        lohi[0] = asinhf(logf(1e-7f * mds) * (float)(2.0 / M_PI));
        lohi[1] = asinhf(logf(1000.0f * mxs) * (float)(2.0 / M_PI));

        ws[P_SCALE] = scale;
        float soft_sc = SOFTV / scale;
        ws[P_SOFT2] = soft_sc * soft_sc;
        ws[P_MGE]   = (float)(2.0 * M_PI) * GRAV * scale * scale;
        const float L2T = 3.321928094887362f;   // log2(10)
        ws[P_BH]    = GRAV * exp2f(mbh[0] * L2T) / scale;
    }
    __syncthreads();

    if (tid == 0) {
        float Rmax = red[0];
        for (int i = 1; i < 128; ++i) Rmax = fmaxf(Rmax, red[i]);
        const float LT2 = 0.3010299956639812f;  // log10(2)
        float lg0 = log10f(SOFTV);
        float lg1 = log10f(Rmax);
        float step = (lg1 - lg0) / (float)(NGRID - 1);
        float istep = 1.0f / step;
        ws[P_FA]    = LT2 * istep;   // f = log2(R)*FA + FB  == (log10(R)-lg0)/step
        ws[P_FB]    = -lg0 * istep;
        ws[P_LG0]   = lg0;
        ws[P_STEP]  = step;
    }

    // per-quadrature-node C/A tables (tid 0..127 = node j; +x for tid<64, -x for tid>=64)
    {
        int i = tid & 63;
        float x = GL.x[i];
        if (tid >= 64) x = -x;
        float w0 = GL.w[i];
        float half = 0.5f * (lohi[1] - lohi[0]);
        float mid  = 0.5f * (lohi[1] + lohi[0]);
        float t  = half * x + mid;
        float u  = expf((float)(M_PI / 2.0) * sinhf(t));
        float du = (float)(M_PI / 2.0) * coshf(t) * u;
        float duw = du * (half * w0);
        float op  = 1.0f + u;
        float base = duw / (op * op);
        for (int k = 0; k < NCOMP; ++k) {
            ws[C_OFF + tid * NCOMP + k] = qi[k] * md[k] * base / sqrtf(qi[k] * qi[k] + u);
            ws[A_OFF + tid * NCOMP + k] = -0.5f / (ssc[k] * ssc[k] * op);
        }
    }
}

// one wave per grid radius: 4096 waves
__global__ void mge_vgrid_kernel(float* __restrict__ ws) {
    int wid  = (blockIdx.x * blockDim.x + threadIdx.x) >> 6;
    int lane = threadIdx.x & 63;
    const float L2T = 3.321928094887362f;
    float lg0 = ws[P_LG0], step = ws[P_STEP], scale = ws[P_SCALE];
    float R   = exp2f((lg0 + (float)wid * step) * L2T);
    float Rsc = R / scale;
    float R2  = Rsc * Rsc;
    const float* __restrict__ C = ws + C_OFF;
    const float* __restrict__ A = ws + A_OFF;
    float s = 0.0f;
    for (int t = lane; t < NTERM; t += 64)
        s += C[t] * __expf(A[t] * R2);
    for (int off = 32; off > 0; off >>= 1)
        s += __shfl_down(s, off);
    if (lane == 0) {
        float vc2 = ws[P_MGE] * s;
        float xq = R2 + ws[P_SOFT2];
        vc2 += ws[P_BH] / (xq * sqrtf(xq));
        ws[VG_OFF + wid] = Rsc * sqrtf(vc2);
    }
}

__global__ void __launch_bounds__(256) mge_interp_kernel(
        const f32x4* __restrict__ Rm, f32x4* __restrict__ out,
        const float* __restrict__ ws, int n4) {
    __shared__ float tv[NGRID];  // 16 KB -> no LDS occupancy cap at 8 blocks/CU
    const float* __restrict__ vg = ws + VG_OFF;
    for (int i = threadIdx.x; i < NGRID; i += 256)
        tv[i] = vg[i];
    __syncthreads();
    float fa = ws[P_FA], fb = ws[P_FB];
    int stride = gridDim.x * blockDim.x;
    for (int idx = blockIdx.x * blockDim.x + threadIdx.x; idx < n4; idx += stride) {
        f32x4 r4 = Rm[idx];
        f32x4 o4;
        #pragma unroll
        for (int e = 0; e < 4; ++e) {
            // continuous log-grid position; R_map >= SOFT > 0 so log2 is safe
            float f = fmaf(__log2f(r4[e]), fa, fb);
            f = fminf(fmaxf(f, 0.0f), (float)(NGRID - 1));
            int lo = min((int)f, NGRID - 2);
            float w = f - (float)lo;            // linear-in-log weight: differs from
            float vlo = tv[lo];                 // exact by <= ~ln10*step/8 * dv ~ 4e-4*dv
            o4[e] = fmaf(w, tv[lo + 1] - vlo, vlo);
        }
        __builtin_nontemporal_store(o4, &out[idx]);
    }
}

extern "C" void kernel_launch(void* const* d_in, const int* in_sizes, int n_in,
                              void* d_out, int out_size, void* d_ws, size_t ws_size,
                              hipStream_t stream) {
    const float* R_map = (const float*)d_in[0];
    const float* surf  = (const float*)d_in[1];
    const float* sigma = (const float*)d_in[2];
    const float* qintr = (const float*)d_in[3];
    const float* MtoL  = (const float*)d_in[4];
    const float* inc   = (const float*)d_in[5];
    const float* mbh   = (const float*)d_in[6];
    float* out = (float*)d_out;
    float* ws  = (float*)d_ws;

    int n4 = out_size / 4;

    mge_max_kernel<<<MAXBLOCKS, 256, 0, stream>>>((const f32x4*)R_map, ws, n4);
    mge_prep_kernel<<<1, 128, 0, stream>>>(surf, sigma, qintr, MtoL, inc, mbh, ws);
    mge_vgrid_kernel<<<NGRID / 4, 256, 0, stream>>>(ws);
    mge_interp_kernel<<<2048, 256, 0, stream>>>((const f32x4*)R_map, (f32x4*)out, ws, n4);
}